// Round 3
// baseline (225.314 us; speedup 1.0000x reference)
//
#include <hip/hip_runtime.h>

#define D1 256
#define H1 128
#define H2 64
#define RT 16          // rows per block
#define FEP 40         // fe row stride (floats)
#define H1P 136        // h1s row stride (floats)

// transposed unified weights: wT[(j*D + d)*O + o], j=0 base, j=1+k spline grid k
#define N1T (9*D1*H1)  // 294912
#define N2T (9*H1*H2)  // 73728

__global__ __launch_bounds__(256) void prep_all(
    const float* __restrict__ bw1x, const float* __restrict__ sw1x,
    const float* __restrict__ bb1x, const float* __restrict__ sb1x,
    const float* __restrict__ bw2x, const float* __restrict__ sw2x,
    const float* __restrict__ bb2x, const float* __restrict__ sb2x,
    const float* __restrict__ bw1y, const float* __restrict__ sw1y,
    const float* __restrict__ bb1y, const float* __restrict__ sb1y,
    const float* __restrict__ bw2y, const float* __restrict__ sw2y,
    const float* __restrict__ bb2y, const float* __restrict__ sb2y,
    float* __restrict__ w1xT, float* __restrict__ w1yT,
    float* __restrict__ w2xT, float* __restrict__ w2yT,
    float* __restrict__ b1x, float* __restrict__ b1y,
    float* __restrict__ b2x, float* __restrict__ b2y)
{
  int i = blockIdx.x * 256 + threadIdx.x;
  if (i < N1T) {
    int o = i & 127; int rest = i >> 7; int d = rest & 255; int j = rest >> 8;
    w1xT[i] = (j == 0) ? bw1x[o*256 + d] : sw1x[o*2048 + d*8 + (j-1)];
  } else if (i < 2*N1T) {
    int i2 = i - N1T;
    int o = i2 & 127; int rest = i2 >> 7; int d = rest & 255; int j = rest >> 8;
    w1yT[i2] = (j == 0) ? bw1y[o*256 + d] : sw1y[o*2048 + d*8 + (j-1)];
  } else if (i < 2*N1T + N2T) {
    int i2 = i - 2*N1T;
    int o = i2 & 63; int rest = i2 >> 6; int d = rest & 127; int j = rest >> 7;
    w2xT[i2] = (j == 0) ? bw2x[o*128 + d] : sw2x[o*1024 + d*8 + (j-1)];
  } else if (i < 2*N1T + 2*N2T) {
    int i2 = i - (2*N1T + N2T);
    int o = i2 & 63; int rest = i2 >> 6; int d = rest & 127; int j = rest >> 7;
    w2yT[i2] = (j == 0) ? bw2y[o*128 + d] : sw2y[o*1024 + d*8 + (j-1)];
  } else {
    int i2 = i - (2*N1T + 2*N2T);
    if (i2 < 128)      b1x[i2]     = bb1x[i2]     + sb1x[i2];
    else if (i2 < 256) b1y[i2-128] = bb1y[i2-128] + sb1y[i2-128];
    else if (i2 < 320) b2x[i2-256] = bb2x[i2-256] + sb2x[i2-256];
    else if (i2 < 384) b2y[i2-320] = bb2y[i2-320] + sb2y[i2-320];
  }
}

__global__ __launch_bounds__(256, 2) void fused_kernel(
    const float* __restrict__ Xx, const float* __restrict__ Xy,
    const float* __restrict__ w1xT, const float* __restrict__ w1yT,
    const float* __restrict__ w2xT, const float* __restrict__ w2yT,
    const float* __restrict__ b1x_, const float* __restrict__ b1y_,
    const float* __restrict__ b2x_, const float* __restrict__ b2y_,
    const float* __restrict__ finw, float* __restrict__ partial)
{
  __shared__ float fe[9*RT*FEP];     // 23040 B
  __shared__ float h1s[RT*H1P];      // 8704 B   -> ~31.7 KB static LDS

  const int t   = threadIdx.x;
  const int sid = blockIdx.x >> 8;   // 0=x, 1=y
  const int rb  = blockIdx.x & 255;

  const float* X  = sid ? Xy   : Xx;
  const float* w1 = sid ? w1yT : w1xT;
  const float* w2 = sid ? w2yT : w2xT;
  const float* b1 = sid ? b1y_ : b1x_;
  const float* b2 = sid ? b2y_ : b2x_;

  const float INVH = 1.75f;  // 1 / (4/7)
  const size_t xbase = (size_t)(rb * RT) * D1;

  // ================= layer 1: every wave reads full out-range ================
  // lane map: tx = t&31 (outs tx*4..tx*4+3), tz = t>>5 (rows tz, tz+8)
  const int tx = t & 31;
  const int tz = t >> 5;

  float acc0[4], acc1[4];
  #pragma unroll
  for (int o = 0; o < 4; ++o) { float b = b1[tx*4 + o]; acc0[o] = b; acc1[o] = b; }

  #pragma unroll 1
  for (int c = 0; c < 8; ++c) {
    __syncthreads();               // previous chunk fully consumed
    // feats: 16 rows x 32 dims x 9 planes (2 elems/thread)
    #pragma unroll
    for (int i = 0; i < 2; ++i) {
      int p = t + i*256;
      int r = p >> 5, dd = p & 31;
      float xv = X[xbase + (size_t)r*D1 + c*32 + dd];
      float e  = __expf(-xv);
      fe[r*FEP + dd] = xv / (1.0f + e);              // silu
      #pragma unroll
      for (int k = 0; k < 8; ++k) {
        float g = -2.0f + (float)k * (4.0f/7.0f);
        float z = (xv - g) * INVH;
        fe[((1+k)*RT + r)*FEP + dd] = __expf(-z*z);
      }
    }
    __syncthreads();

    #pragma unroll 1
    for (int j = 0; j < 9; ++j) {
      const float* wj = w1 + (size_t)(j*D1 + c*32)*H1 + tx*4;
      const float* fb = fe + (j*RT + tz)*FEP;
      #pragma unroll
      for (int g = 0; g < 8; ++g) {
        float4 fA = *(const float4*)(fb + g*4);
        float4 fB = *(const float4*)(fb + 8*FEP + g*4);
        #pragma unroll
        for (int dd = 0; dd < 4; ++dd) {
          float4 w = *(const float4*)(wj + (size_t)(g*4 + dd)*H1);
          float fa  = (&fA.x)[dd];
          float fbv = (&fB.x)[dd];
          acc0[0] += fa*w.x;  acc0[1] += fa*w.y;  acc0[2] += fa*w.z;  acc0[3] += fa*w.w;
          acc1[0] += fbv*w.x; acc1[1] += fbv*w.y; acc1[2] += fbv*w.z; acc1[3] += fbv*w.w;
        }
      }
    }
  }

  __syncthreads();
  *(float4*)(h1s + tz*H1P + tx*4)     = make_float4(acc0[0], acc0[1], acc0[2], acc0[3]);
  *(float4*)(h1s + (tz+8)*H1P + tx*4) = make_float4(acc1[0], acc1[1], acc1[2], acc1[3]);

  // ================= layer 2: K = 128 dims x 9 planes -> 64 outs ==============
  // lane map: tx2 = t&15 (outs tx2*4..), tz2 = t>>4 (row tz2), R=1
  const int tx2 = t & 15;
  const int tz2 = t >> 4;

  float a2[4];
  #pragma unroll
  for (int o = 0; o < 4; ++o) a2[o] = b2[tx2*4 + o];

  #pragma unroll 1
  for (int c = 0; c < 4; ++c) {
    __syncthreads();
    #pragma unroll
    for (int i = 0; i < 2; ++i) {
      int p = t + i*256;
      int r = p >> 5, dd = p & 31;
      float xv = h1s[r*H1P + c*32 + dd];
      float e  = __expf(-xv);
      fe[r*FEP + dd] = xv / (1.0f + e);
      #pragma unroll
      for (int k = 0; k < 8; ++k) {
        float g = -2.0f + (float)k * (4.0f/7.0f);
        float z = (xv - g) * INVH;
        fe[((1+k)*RT + r)*FEP + dd] = __expf(-z*z);
      }
    }
    __syncthreads();

    #pragma unroll 1
    for (int j = 0; j < 9; ++j) {
      const float* wj = w2 + (size_t)(j*H1 + c*32)*H2 + tx2*4;
      const float* fb = fe + (j*RT + tz2)*FEP;
      #pragma unroll
      for (int g = 0; g < 8; ++g) {
        float4 fA = *(const float4*)(fb + g*4);
        #pragma unroll
        for (int dd = 0; dd < 4; ++dd) {
          float4 w = *(const float4*)(wj + (size_t)(g*4 + dd)*H2);
          float fa = (&fA.x)[dd];
          a2[0] += fa*w.x; a2[1] += fa*w.y; a2[2] += fa*w.z; a2[3] += fa*w.w;
        }
      }
    }
  }

  // ---- final dot + block reduce (reuse fe as scratch) ----
  const float* wf = finw + sid*64;
  float pz = a2[0]*wf[tx2*4] + a2[1]*wf[tx2*4+1] + a2[2]*wf[tx2*4+2] + a2[3]*wf[tx2*4+3];

  __syncthreads();
  float* red = fe;
  red[t] = pz;
  __syncthreads();
  #pragma unroll 1
  for (int sft = 128; sft > 0; sft >>= 1) {
    if (t < sft) red[t] += red[t + sft];
    __syncthreads();
  }
  if (t == 0) partial[sid*256 + rb] = red[0];
}

__global__ __launch_bounds__(256) void reduce_kernel(
    const float* __restrict__ partial, const float* __restrict__ finb,
    float* __restrict__ out)
{
  int t = threadIdx.x;
  int b = t >> 6, i = t & 63;
  float v = partial[b*64 + i] + partial[256 + b*64 + i];
  #pragma unroll
  for (int off = 32; off > 0; off >>= 1) v += __shfl_down(v, off, 64);
  if (i == 0) out[b] = finb[0] + v * (1.0f/1024.0f);
}

extern "C" void kernel_launch(void* const* d_in, const int* in_sizes, int n_in,
                              void* d_out, int out_size, void* d_ws, size_t ws_size,
                              hipStream_t stream)
{
  (void)in_sizes; (void)n_in; (void)out_size; (void)ws_size;
  const float* x    = (const float*)d_in[0];
  const float* y    = (const float*)d_in[1];
  const float* bw1x = (const float*)d_in[2];
  const float* bb1x = (const float*)d_in[3];
  const float* sw1x = (const float*)d_in[4];
  const float* sb1x = (const float*)d_in[5];
  const float* bw2x = (const float*)d_in[6];
  const float* bb2x = (const float*)d_in[7];
  const float* sw2x = (const float*)d_in[8];
  const float* sb2x = (const float*)d_in[9];
  const float* bw1y = (const float*)d_in[10];
  const float* bb1y = (const float*)d_in[11];
  const float* sw1y = (const float*)d_in[12];
  const float* sb1y = (const float*)d_in[13];
  const float* bw2y = (const float*)d_in[14];
  const float* bb2y = (const float*)d_in[15];
  const float* sw2y = (const float*)d_in[16];
  const float* sb2y = (const float*)d_in[17];
  const float* finw = (const float*)d_in[18];
  const float* finb = (const float*)d_in[19];

  float* ws = (float*)d_ws;
  float* w1xT = ws;               // 294912
  float* w1yT = w1xT + N1T;
  float* w2xT = w1yT + N1T;       // 73728
  float* w2yT = w2xT + N2T;
  float* b1x  = w2yT + N2T;       // 128
  float* b1y  = b1x + 128;
  float* b2x  = b1y + 128;        // 64
  float* b2y  = b2x + 64;
  float* partial = b2y + 64;      // 512

  int prep_blocks = (2*N1T + 2*N2T + 384 + 255) / 256;
  hipLaunchKernelGGL(prep_all, dim3(prep_blocks), dim3(256), 0, stream,
                     bw1x, sw1x, bb1x, sb1x, bw2x, sw2x, bb2x, sb2x,
                     bw1y, sw1y, bb1y, sb1y, bw2y, sw2y, bb2y, sb2y,
                     w1xT, w1yT, w2xT, w2yT, b1x, b1y, b2x, b2y);

  hipLaunchKernelGGL(fused_kernel, dim3(512), dim3(256), 0, stream,
                     x, y, w1xT, w1yT, w2xT, w2yT, b1x, b1y, b2x, b2y,
                     finw, partial);

  hipLaunchKernelGGL(reduce_kernel, dim3(1), dim3(256), 0, stream,
                     partial, finb, (float*)d_out);
}

// Round 5
// 44.904 us; speedup vs baseline: 5.0177x; 5.0177x over previous
//
#include <hip/hip_runtime.h>

typedef __attribute__((ext_vector_type(8))) short short8;
typedef __attribute__((ext_vector_type(16))) float floatx16;

#define B1SLOTS 1152      // 8 waves * 18 K16-steps * 4 ncol * 2 pass
#define B2SLOTS 288       // 8 waves * 9 K16-steps * 2 ncol * 2 pass
#define B1LS (B1SLOTS*64)
#define B2LS (B2SLOTS*64)

__device__ __forceinline__ unsigned short f2bf(float f) {
  union { float f; unsigned u; } v; v.f = f;
  unsigned r = v.u + 0x7fffu + ((v.u >> 16) & 1u);
  return (unsigned short)(r >> 16);
}
__device__ __forceinline__ float bf2f(unsigned short h) {
  union { unsigned u; float f; } v; v.u = ((unsigned)h) << 16;
  return v.f;
}

// ---------------- prep: weights -> bf16 hi/lo MFMA fragment order ----------------
__global__ __launch_bounds__(256) void prep_frags(
    const float* __restrict__ bw1x, const float* __restrict__ sw1x,
    const float* __restrict__ bb1x, const float* __restrict__ sb1x,
    const float* __restrict__ bw2x, const float* __restrict__ sw2x,
    const float* __restrict__ bb2x, const float* __restrict__ sb2x,
    const float* __restrict__ bw1y, const float* __restrict__ sw1y,
    const float* __restrict__ bb1y, const float* __restrict__ sb1y,
    const float* __restrict__ bw2y, const float* __restrict__ sw2y,
    const float* __restrict__ bb2y, const float* __restrict__ sb2y,
    uint4* __restrict__ B1fx, uint4* __restrict__ B1fy,
    uint4* __restrict__ B2fx, uint4* __restrict__ B2fy,
    float* __restrict__ b1x, float* __restrict__ b1y,
    float* __restrict__ b2x, float* __restrict__ b2y)
{
  int idx = blockIdx.x * 256 + threadIdx.x;
  if (idx < 2 * B1LS) {
    int sid = idx / B1LS;
    int ls  = idx - sid * B1LS;
    const float* bw = sid ? bw1y : bw1x;
    const float* sw = sid ? sw1y : sw1x;
    uint4* dst = sid ? B1fy : B1fx;
    int l = ls & 63, slot = ls >> 6;
    int p = slot & 1, nc = (slot >> 1) & 3, tw = slot >> 3;  // tw = w*18 + t
    int t = tw % 18, w = tw / 18;
    int j = t >> 1, ks = t & 1;
    int o = nc * 32 + (l & 31);
    int dbase = w * 32 + ks * 16 + (l >> 5) * 8;
    unsigned short e[8];
    #pragma unroll
    for (int i = 0; i < 8; ++i) {
      int d = dbase + i;
      float wv = (j == 0) ? bw[o * 256 + d] : sw[o * 2048 + d * 8 + (j - 1)];
      unsigned short hi = f2bf(wv);
      e[i] = p ? f2bf(wv - bf2f(hi)) : hi;
    }
    uint4 out;
    out.x = (unsigned)e[0] | ((unsigned)e[1] << 16);
    out.y = (unsigned)e[2] | ((unsigned)e[3] << 16);
    out.z = (unsigned)e[4] | ((unsigned)e[5] << 16);
    out.w = (unsigned)e[6] | ((unsigned)e[7] << 16);
    dst[ls] = out;
  } else if (idx < 2 * B1LS + 2 * B2LS) {
    int i2 = idx - 2 * B1LS;
    int sid = i2 / B2LS;
    int ls  = i2 - sid * B2LS;
    const float* bw = sid ? bw2y : bw2x;
    const float* sw = sid ? sw2y : sw2x;
    uint4* dst = sid ? B2fy : B2fx;
    int l = ls & 63, slot = ls >> 6;
    int p = slot & 1, nc = (slot >> 1) & 1, tw = slot >> 2;  // tw = w*9 + j2
    int j2 = tw % 9, w = tw / 9;
    int o = nc * 32 + (l & 31);
    int dbase = w * 16 + (l >> 5) * 8;
    unsigned short e[8];
    #pragma unroll
    for (int i = 0; i < 8; ++i) {
      int d = dbase + i;
      float wv = (j2 == 0) ? bw[o * 128 + d] : sw[o * 1024 + d * 8 + (j2 - 1)];
      unsigned short hi = f2bf(wv);
      e[i] = p ? f2bf(wv - bf2f(hi)) : hi;
    }
    uint4 out;
    out.x = (unsigned)e[0] | ((unsigned)e[1] << 16);
    out.y = (unsigned)e[2] | ((unsigned)e[3] << 16);
    out.z = (unsigned)e[4] | ((unsigned)e[5] << 16);
    out.w = (unsigned)e[6] | ((unsigned)e[7] << 16);
    dst[ls] = out;
  } else {
    int i2 = idx - (2 * B1LS + 2 * B2LS);
    if (i2 < 128)      b1x[i2]       = bb1x[i2]       + sb1x[i2];
    else if (i2 < 256) b1y[i2 - 128] = bb1y[i2 - 128] + sb1y[i2 - 128];
    else if (i2 < 320) b2x[i2 - 256] = bb2x[i2 - 256] + sb2x[i2 - 256];
    else if (i2 < 384) b2y[i2 - 320] = bb2y[i2 - 320] + sb2y[i2 - 320];
  }
}

// ---------------- fused: both layers + final dot, one block per 32 rows ----------------
#define XSP 264

__global__ __launch_bounds__(512, 2) void fused_kernel(
    const float* __restrict__ Xx, const float* __restrict__ Xy,
    const uint4* __restrict__ B1fx, const uint4* __restrict__ B1fy,
    const uint4* __restrict__ B2fx, const uint4* __restrict__ B2fy,
    const float* __restrict__ b1x_, const float* __restrict__ b1y_,
    const float* __restrict__ b2x_, const float* __restrict__ b2y_,
    const float* __restrict__ finw, float* __restrict__ partial)
{
  __shared__ float xs[32 * XSP];    // 33792 B; reused as 2 x 16KB reduce buffers
  __shared__ float h1s[32 * 136];   // 17408 B
  __shared__ float redw[8];

  const int tid  = threadIdx.x;
  const int bid  = blockIdx.x;
  const int sid  = bid >> 7;         // 0=x, 1=y
  const int mb   = bid & 127;        // 32-row tile index
  const int wave = tid >> 6;
  const int l    = tid & 63;
  const int lc   = l & 31;           // A-row / C-col
  const int lk   = l >> 5;           // k half

  const float* X  = sid ? Xy : Xx;
  const uint4* B1 = sid ? B1fy : B1fx;
  const uint4* B2 = sid ? B2fy : B2fx;
  const float* b1 = sid ? b1y_ : b1x_;
  const float* b2 = sid ? b2y_ : b2x_;

  // ---- stage x tile: 32 rows x 256, coalesced ----
  {
    int row = tid >> 4, col = (tid & 15) * 16;
    const float* src = X + (size_t)(mb * 32 + row) * 256 + col;
    #pragma unroll
    for (int q = 0; q < 4; ++q)
      *(float4*)(xs + row * XSP + col + q * 4) = *(const float4*)(src + q * 4);
  }
  __syncthreads();

  // ================= layer 1: wave owns 32 input dims (x 9 planes) ============
  floatx16 acc[4] = {};
  float xr[16];
  {
    const int d0 = wave * 32;
    #pragma unroll
    for (int q = 0; q < 2; ++q) {
      float4 v = *(const float4*)(xs + lc * XSP + d0 + lk * 8 + q * 4);
      xr[q*4+0] = v.x; xr[q*4+1] = v.y; xr[q*4+2] = v.z; xr[q*4+3] = v.w;
      float4 u = *(const float4*)(xs + lc * XSP + d0 + 16 + lk * 8 + q * 4);
      xr[8+q*4+0] = u.x; xr[8+q*4+1] = u.y; xr[8+q*4+2] = u.z; xr[8+q*4+3] = u.w;
    }
  }
  __syncthreads();   // all A-frags in regs; xs free for reduction buffers

  #pragma unroll 1
  for (int j = 0; j < 9; ++j) {
    uint4 bf[16];
    {
      size_t sb = (size_t)((wave * 18 + j * 2) * 8) * 64 + l;
      #pragma unroll
      for (int q = 0; q < 16; ++q) bf[q] = B1[sb + (size_t)q * 64];
    }
    float f0[8], f1[8];
    if (j == 0) {
      #pragma unroll
      for (int i = 0; i < 8; ++i) {
        f0[i] = __fdividef(xr[i],     1.f + __expf(-xr[i]));
        f1[i] = __fdividef(xr[8 + i], 1.f + __expf(-xr[8 + i]));
      }
    } else {
      float g = -2.f + (float)(j - 1) * (4.f / 7.f);
      #pragma unroll
      for (int i = 0; i < 8; ++i) {
        float z0 = (xr[i] - g) * 1.75f;
        float z1 = (xr[8 + i] - g) * 1.75f;
        f0[i] = __expf(-z0 * z0);
        f1[i] = __expf(-z1 * z1);
      }
    }
    short8 a0h, a0l, a1h, a1l;
    #pragma unroll
    for (int i = 0; i < 8; ++i) {
      unsigned short h0 = f2bf(f0[i]);
      unsigned short h1 = f2bf(f1[i]);
      a0h[i] = (short)h0; a0l[i] = (short)f2bf(f0[i] - bf2f(h0));
      a1h[i] = (short)h1; a1l[i] = (short)f2bf(f1[i] - bf2f(h1));
    }
    #pragma unroll
    for (int nc = 0; nc < 4; ++nc) {
      short8 bh0 = __builtin_bit_cast(short8, bf[nc*2+0]);
      short8 bl0 = __builtin_bit_cast(short8, bf[nc*2+1]);
      short8 bh1 = __builtin_bit_cast(short8, bf[8+nc*2+0]);
      short8 bl1 = __builtin_bit_cast(short8, bf[8+nc*2+1]);
      acc[nc] = __builtin_amdgcn_mfma_f32_32x32x16_bf16(a0h, bh0, acc[nc], 0, 0, 0);
      acc[nc] = __builtin_amdgcn_mfma_f32_32x32x16_bf16(a0h, bl0, acc[nc], 0, 0, 0);
      acc[nc] = __builtin_amdgcn_mfma_f32_32x32x16_bf16(a0l, bh0, acc[nc], 0, 0, 0);
      acc[nc] = __builtin_amdgcn_mfma_f32_32x32x16_bf16(a1h, bh1, acc[nc], 0, 0, 0);
      acc[nc] = __builtin_amdgcn_mfma_f32_32x32x16_bf16(a1h, bl1, acc[nc], 0, 0, 0);
      acc[nc] = __builtin_amdgcn_mfma_f32_32x32x16_bf16(a1l, bh1, acc[nc], 0, 0, 0);
    }
  }

  // ---- cross-wave K reduction: 8 partials of 32x128, 2 buffers, race-free ----
  float* S0 = xs;
  float* S1 = xs + 4096;
  auto store1 = [&](float* Sb) {
    #pragma unroll
    for (int nc = 0; nc < 4; ++nc)
      #pragma unroll
      for (int r = 0; r < 16; ++r) {
        int row = (r & 3) + 8 * (r >> 2) + 4 * lk;
        Sb[row * 128 + nc * 32 + lc] = acc[nc][r];
      }
  };
  auto add1 = [&](const float* Sb) {
    #pragma unroll
    for (int nc = 0; nc < 4; ++nc)
      #pragma unroll
      for (int r = 0; r < 16; ++r) {
        int row = (r & 3) + 8 * (r >> 2) + 4 * lk;
        acc[nc][r] += Sb[row * 128 + nc * 32 + lc];
      }
  };
  __syncthreads();
  if (wave == 1) store1(S0);
  if (wave == 3) store1(S1);
  __syncthreads();
  if (wave == 0) add1(S0);          // w0 = 0+1
  if (wave == 2) add1(S1);          // w2 = 2+3
  __syncthreads();
  if (wave == 5) store1(S0);
  if (wave == 7) store1(S1);
  __syncthreads();
  if (wave == 4) add1(S0);          // w4 = 4+5
  if (wave == 6) add1(S1);          // w6 = 6+7
  __syncthreads();
  if (wave == 2) store1(S0);
  if (wave == 6) store1(S1);
  __syncthreads();
  if (wave == 0) add1(S0);          // w0 = 0..3
  if (wave == 4) add1(S1);          // w4 = 4..7
  __syncthreads();
  if (wave == 4) store1(S0);
  __syncthreads();
  if (wave == 0) {
    add1(S0);                       // w0 = full sum
    #pragma unroll
    for (int nc = 0; nc < 4; ++nc)
      #pragma unroll
      for (int r = 0; r < 16; ++r) {
        int row = (r & 3) + 8 * (r >> 2) + 4 * lk;
        int col = nc * 32 + lc;
        h1s[row * 136 + col] = acc[nc][r] + b1[col];
      }
  }
  __syncthreads();

  // ================= layer 2: wave owns 16 h1 dims (x 9 planes) ===============
  floatx16 acc2[2] = {};
  float hr[8];
  {
    const int d2 = wave * 16 + lk * 8;
    float4 v = *(const float4*)(h1s + lc * 136 + d2);
    float4 u = *(const float4*)(h1s + lc * 136 + d2 + 4);
    hr[0]=v.x; hr[1]=v.y; hr[2]=v.z; hr[3]=v.w;
    hr[4]=u.x; hr[5]=u.y; hr[6]=u.z; hr[7]=u.w;
  }

  #pragma unroll 1
  for (int j2 = 0; j2 < 9; ++j2) {
    uint4 bf[4];
    {
      size_t sb = (size_t)((wave * 9 + j2) * 4) * 64 + l;
      #pragma unroll
      for (int q = 0; q < 4; ++q) bf[q] = B2[sb + (size_t)q * 64];
    }
    float f[8];
    if (j2 == 0) {
      #pragma unroll
      for (int i = 0; i < 8; ++i)
        f[i] = __fdividef(hr[i], 1.f + __expf(-hr[i]));
    } else {
      float g = -2.f + (float)(j2 - 1) * (4.f / 7.f);
      #pragma unroll
      for (int i = 0; i < 8; ++i) {
        float z = (hr[i] - g) * 1.75f;
        f[i] = __expf(-z * z);
      }
    }
    short8 ah, al;
    #pragma unroll
    for (int i = 0; i < 8; ++i) {
      unsigned short h = f2bf(f[i]);
      ah[i] = (short)h; al[i] = (short)f2bf(f[i] - bf2f(h));
    }
    #pragma unroll
    for (int nc = 0; nc < 2; ++nc) {
      short8 bh = __builtin_bit_cast(short8, bf[nc*2+0]);
      short8 bl = __builtin_bit_cast(short8, bf[nc*2+1]);
      acc2[nc] = __builtin_amdgcn_mfma_f32_32x32x16_bf16(ah, bh, acc2[nc], 0, 0, 0);
      acc2[nc] = __builtin_amdgcn_mfma_f32_32x32x16_bf16(ah, bl, acc2[nc], 0, 0, 0);
      acc2[nc] = __builtin_amdgcn_mfma_f32_32x32x16_bf16(al, bh, acc2[nc], 0, 0, 0);
    }
  }

  // ---- no layer-2 tree: each wave dots its K-partial with final_w directly ----
  const float* wf = finw + sid * 64;
  {
    float w0 = wf[lc], w1v = wf[32 + lc];
    float pz = 0.f;
    #pragma unroll
    for (int r = 0; r < 16; ++r) pz += acc2[0][r] * w0 + acc2[1][r] * w1v;
    #pragma unroll
    for (int off = 32; off > 0; off >>= 1) pz += __shfl_down(pz, off, 64);
    if (l == 0) redw[wave] = pz;
  }
  __syncthreads();
  if (wave == 0) {
    float v = (l < 8) ? redw[l] : 0.f;
    v += 32.f * b2[l] * wf[l];         // bias contribution: 32 rows x sum_o b2[o]*wf[o]
    #pragma unroll
    for (int off = 32; off > 0; off >>= 1) v += __shfl_down(v, off, 64);
    if (l == 0) partial[bid] = v;
  }
}

// ---------------- final reduce: 256 block-partials -> 4 outputs ----------------
__global__ __launch_bounds__(256) void final_kernel(
    const float* __restrict__ partial, const float* __restrict__ finb,
    float* __restrict__ out)
{
  __shared__ float red[4][64];
  int t = threadIdx.x;
  int batch = (t & 127) >> 5;
  int slot  = (t >> 7) * 32 + (t & 31);
  red[batch][slot] = partial[t];
  __syncthreads();
  if (t < 4) {
    float s = 0.f;
    for (int i = 0; i < 64; ++i) s += red[t][i];
    out[t] = finb[0] + s * (1.0f / 1024.0f);
  }
}

extern "C" void kernel_launch(void* const* d_in, const int* in_sizes, int n_in,
                              void* d_out, int out_size, void* d_ws, size_t ws_size,
                              hipStream_t stream)
{
  (void)in_sizes; (void)n_in; (void)out_size; (void)ws_size;
  const float* x    = (const float*)d_in[0];
  const float* y    = (const float*)d_in[1];
  const float* bw1x = (const float*)d_in[2];
  const float* bb1x = (const float*)d_in[3];
  const float* sw1x = (const float*)d_in[4];
  const float* sb1x = (const float*)d_in[5];
  const float* bw2x = (const float*)d_in[6];
  const float* bb2x = (const float*)d_in[7];
  const float* sw2x = (const float*)d_in[8];
  const float* sb2x = (const float*)d_in[9];
  const float* bw1y = (const float*)d_in[10];
  const float* bb1y = (const float*)d_in[11];
  const float* sw1y = (const float*)d_in[12];
  const float* sb1y = (const float*)d_in[13];
  const float* bw2y = (const float*)d_in[14];
  const float* bb2y = (const float*)d_in[15];
  const float* sw2y = (const float*)d_in[16];
  const float* sb2y = (const float*)d_in[17];
  const float* finw = (const float*)d_in[18];
  const float* finb = (const float*)d_in[19];

  char* ws = (char*)d_ws;
  uint4* B1fx = (uint4*)(ws);
  uint4* B1fy = (uint4*)(ws + 1179648);
  uint4* B2fx = (uint4*)(ws + 2359296);
  uint4* B2fy = (uint4*)(ws + 2654208);
  float* b1x  = (float*)(ws + 2949120);
  float* b1y  = b1x + 128;
  float* b2x  = b1y + 128;
  float* b2y  = b2x + 64;
  float* partial = b2y + 64;   // 256 floats

  int prep_total = 2 * B1LS + 2 * B2LS + 384;
  int prep_blocks = (prep_total + 255) / 256;
  hipLaunchKernelGGL(prep_frags, dim3(prep_blocks), dim3(256), 0, stream,
                     bw1x, sw1x, bb1x, sb1x, bw2x, sw2x, bb2x, sb2x,
                     bw1y, sw1y, bb1y, sb1y, bw2y, sw2y, bb2y, sb2y,
                     B1fx, B1fy, B2fx, B2fy, b1x, b1y, b2x, b2y);

  hipLaunchKernelGGL(fused_kernel, dim3(256), dim3(512), 0, stream,
                     x, y, B1fx, B1fy, B2fx, B2fy, b1x, b1y, b2x, b2y,
                     finw, partial);

  hipLaunchKernelGGL(final_kernel, dim3(1), dim3(256), 0, stream,
                     partial, finb, (float*)d_out);
}

// Round 6
// 44.548 us; speedup vs baseline: 5.0578x; 1.0080x over previous
//
#include <hip/hip_runtime.h>

typedef __attribute__((ext_vector_type(8))) short short8;
typedef __attribute__((ext_vector_type(16))) float floatx16;

// B1 frag layout: per sid, q = (ds*9 + j)*4 + nc  (ds in [0,16), j in [0,9), nc in [0,4))
//   uint4 slot addr = q*128 + p*64 + l   (p = 0 hi, 1 lo; l = lane)
// B2 frag layout: per sid, q2 = (w*9 + j)*2 + nc (w in [0,8), nc in [0,2))
//   uint4 slot addr = q2*128 + p*64 + l
#define B1U 73728   // uint4 per sid = 576*128
#define B2U 18432   // uint4 per sid = 144*128

__device__ __forceinline__ unsigned short f2bf(float f) {
  union { float f; unsigned u; } v; v.f = f;
  unsigned r = v.u + 0x7fffu + ((v.u >> 16) & 1u);
  return (unsigned short)(r >> 16);
}
__device__ __forceinline__ float bf2f(unsigned short h) {
  union { unsigned u; float f; } v; v.u = ((unsigned)h) << 16;
  return v.f;
}

__global__ __launch_bounds__(256) void prep_frags(
    const float* __restrict__ bw1x, const float* __restrict__ sw1x,
    const float* __restrict__ bb1x, const float* __restrict__ sb1x,
    const float* __restrict__ bw2x, const float* __restrict__ sw2x,
    const float* __restrict__ bb2x, const float* __restrict__ sb2x,
    const float* __restrict__ bw1y, const float* __restrict__ sw1y,
    const float* __restrict__ bb1y, const float* __restrict__ sb1y,
    const float* __restrict__ bw2y, const float* __restrict__ sw2y,
    const float* __restrict__ bb2y, const float* __restrict__ sb2y,
    uint4* __restrict__ B1fx, uint4* __restrict__ B1fy,
    uint4* __restrict__ B2fx, uint4* __restrict__ B2fy,
    float* __restrict__ b1x, float* __restrict__ b1y,
    float* __restrict__ b2x, float* __restrict__ b2y)
{
  int idx = blockIdx.x * 256 + threadIdx.x;
  if (idx < 2 * 36864) {                       // B1: 2 sids x 576 q x 64 l
    int sid = idx / 36864;
    int rem = idx - sid * 36864;
    int q = rem >> 6, l = rem & 63;
    int nc = q & 3, t9 = q >> 2;
    int j = t9 % 9, ds = t9 / 9;
    const float* bw = sid ? bw1y : bw1x;
    const float* sw = sid ? sw1y : sw1x;
    uint4* dst = sid ? B1fy : B1fx;
    int o = nc * 32 + (l & 31);
    int dbase = ds * 16 + (l >> 5) * 8;
    unsigned short eh[8], el[8];
    #pragma unroll
    for (int i = 0; i < 8; ++i) {
      int d = dbase + i;
      float wv = (j == 0) ? bw[o * 256 + d] : sw[o * 2048 + d * 8 + (j - 1)];
      unsigned short hi = f2bf(wv);
      eh[i] = hi;
      el[i] = f2bf(wv - bf2f(hi));
    }
    uint4 oh, ol;
    oh.x = (unsigned)eh[0] | ((unsigned)eh[1] << 16);
    oh.y = (unsigned)eh[2] | ((unsigned)eh[3] << 16);
    oh.z = (unsigned)eh[4] | ((unsigned)eh[5] << 16);
    oh.w = (unsigned)eh[6] | ((unsigned)eh[7] << 16);
    ol.x = (unsigned)el[0] | ((unsigned)el[1] << 16);
    ol.y = (unsigned)el[2] | ((unsigned)el[3] << 16);
    ol.z = (unsigned)el[4] | ((unsigned)el[5] << 16);
    ol.w = (unsigned)el[6] | ((unsigned)el[7] << 16);
    dst[q * 128 + l]      = oh;
    dst[q * 128 + 64 + l] = ol;
  } else if (idx < 2 * 36864 + 2 * 9216) {     // B2: 2 sids x 144 q2 x 64 l
    int i2 = idx - 2 * 36864;
    int sid = i2 / 9216;
    int rem = i2 - sid * 9216;
    int q2 = rem >> 6, l = rem & 63;
    int nc = q2 & 1, t9 = q2 >> 1;
    int j = t9 % 9, w = t9 / 9;
    const float* bw = sid ? bw2y : bw2x;
    const float* sw = sid ? sw2y : sw2x;
    uint4* dst = sid ? B2fy : B2fx;
    int o = nc * 32 + (l & 31);
    int dbase = w * 16 + (l >> 5) * 8;
    unsigned short eh[8], el[8];
    #pragma unroll
    for (int i = 0; i < 8; ++i) {
      int d = dbase + i;
      float wv = (j == 0) ? bw[o * 128 + d] : sw[o * 1024 + d * 8 + (j - 1)];
      unsigned short hi = f2bf(wv);
      eh[i] = hi;
      el[i] = f2bf(wv - bf2f(hi));
    }
    uint4 oh, ol;
    oh.x = (unsigned)eh[0] | ((unsigned)eh[1] << 16);
    oh.y = (unsigned)eh[2] | ((unsigned)eh[3] << 16);
    oh.z = (unsigned)eh[4] | ((unsigned)eh[5] << 16);
    oh.w = (unsigned)eh[6] | ((unsigned)eh[7] << 16);
    ol.x = (unsigned)el[0] | ((unsigned)el[1] << 16);
    ol.y = (unsigned)el[2] | ((unsigned)el[3] << 16);
    ol.z = (unsigned)el[4] | ((unsigned)el[5] << 16);
    ol.w = (unsigned)el[6] | ((unsigned)el[7] << 16);
    dst[q2 * 128 + l]      = oh;
    dst[q2 * 128 + 64 + l] = ol;
  } else {
    int i2 = idx - (2 * 36864 + 2 * 9216);
    if (i2 < 0) return;
    if (i2 < 128)      b1x[i2]       = bb1x[i2]       + sb1x[i2];
    else if (i2 < 256) b1y[i2 - 128] = bb1y[i2 - 128] + sb1y[i2 - 128];
    else if (i2 < 320) b2x[i2 - 256] = bb2x[i2 - 256] + sb2x[i2 - 256];
    else if (i2 < 384) b2y[i2 - 320] = bb2y[i2 - 320] + sb2y[i2 - 320];
  }
}

// ---------- phase1: layer1, block = (sid, 64-row tile m, K-half s) ----------
__global__ __launch_bounds__(512) void phase1_kernel(
    const float* __restrict__ Xx, const float* __restrict__ Xy,
    const uint4* __restrict__ B1fx, const uint4* __restrict__ B1fy,
    float* __restrict__ hp)
{
  __shared__ float xsh[64 * 132];   // 33.8 KB
  __shared__ float S0[64 * 128];    // 32 KB
  __shared__ float S1[64 * 128];    // 32 KB

  const int t    = threadIdx.x;
  const int bid  = blockIdx.x;
  const int sid  = bid >> 7;
  const int rem  = bid & 127;
  const int m    = rem >> 1;
  const int s    = rem & 1;
  const int wave = t >> 6;
  const int l    = t & 63;
  const int lc   = l & 31;
  const int lk   = l >> 5;

  const float* X  = sid ? Xy : Xx;
  const uint4* B1 = sid ? B1fy : B1fx;

  // stage 64 rows x 128 cols (this block's K-half), coalesced
  {
    int r = t >> 3, c8 = (t & 7) * 16;
    const float* src = X + (size_t)(m * 64 + r) * 256 + s * 128 + c8;
    #pragma unroll
    for (int q = 0; q < 4; ++q)
      *(float4*)(xsh + r * 132 + c8 + q * 4) = *(const float4*)(src + q * 4);
  }
  __syncthreads();

  // per-lane A data: rows lc and lc+32, dims wave*16 + lk*8 + [0,8)
  float xr0[8], xr1[8];
  {
    int cb = wave * 16 + lk * 8;
    float4 v0 = *(const float4*)(xsh + lc * 132 + cb);
    float4 v1 = *(const float4*)(xsh + lc * 132 + cb + 4);
    float4 u0 = *(const float4*)(xsh + (lc + 32) * 132 + cb);
    float4 u1 = *(const float4*)(xsh + (lc + 32) * 132 + cb + 4);
    xr0[0]=v0.x; xr0[1]=v0.y; xr0[2]=v0.z; xr0[3]=v0.w;
    xr0[4]=v1.x; xr0[5]=v1.y; xr0[6]=v1.z; xr0[7]=v1.w;
    xr1[0]=u0.x; xr1[1]=u0.y; xr1[2]=u0.z; xr1[3]=u0.w;
    xr1[4]=u1.x; xr1[5]=u1.y; xr1[6]=u1.z; xr1[7]=u1.w;
  }

  floatx16 acc[2][4] = {};
  const int ds = s * 8 + wave;

  #pragma unroll 1
  for (int j = 0; j < 9; ++j) {
    const uint4* bp = B1 + (size_t)((ds * 9 + j) * 4) * 128 + l;
    uint4 bf[8];
    #pragma unroll
    for (int nc = 0; nc < 4; ++nc) {
      bf[nc * 2]     = bp[nc * 128];
      bf[nc * 2 + 1] = bp[nc * 128 + 64];
    }
    float f0[8], f1[8];
    if (j == 0) {
      #pragma unroll
      for (int i = 0; i < 8; ++i) {
        f0[i] = __fdividef(xr0[i], 1.f + __expf(-xr0[i]));
        f1[i] = __fdividef(xr1[i], 1.f + __expf(-xr1[i]));
      }
    } else {
      float g = -2.f + (float)(j - 1) * (4.f / 7.f);
      #pragma unroll
      for (int i = 0; i < 8; ++i) {
        float z0 = (xr0[i] - g) * 1.75f;
        float z1 = (xr1[i] - g) * 1.75f;
        f0[i] = __expf(-z0 * z0);
        f1[i] = __expf(-z1 * z1);
      }
    }
    short8 a0, a1;
    #pragma unroll
    for (int i = 0; i < 8; ++i) {
      a0[i] = (short)f2bf(f0[i]);
      a1[i] = (short)f2bf(f1[i]);
    }
    #pragma unroll
    for (int nc = 0; nc < 4; ++nc) {
      short8 bh = __builtin_bit_cast(short8, bf[nc * 2]);
      short8 bl = __builtin_bit_cast(short8, bf[nc * 2 + 1]);
      acc[0][nc] = __builtin_amdgcn_mfma_f32_32x32x16_bf16(a0, bh, acc[0][nc], 0, 0, 0);
      acc[0][nc] = __builtin_amdgcn_mfma_f32_32x32x16_bf16(a0, bl, acc[0][nc], 0, 0, 0);
      acc[1][nc] = __builtin_amdgcn_mfma_f32_32x32x16_bf16(a1, bh, acc[1][nc], 0, 0, 0);
      acc[1][nc] = __builtin_amdgcn_mfma_f32_32x32x16_bf16(a1, bl, acc[1][nc], 0, 0, 0);
    }
  }

  // cross-wave K reduction over 8 waves (64x128 tile), race-free tree
  auto st = [&](float* Sb) {
    #pragma unroll
    for (int g = 0; g < 2; ++g)
      #pragma unroll
      for (int nc = 0; nc < 4; ++nc)
        #pragma unroll
        for (int r = 0; r < 16; ++r) {
          int row = g * 32 + (r & 3) + 8 * (r >> 2) + 4 * lk;
          Sb[row * 128 + nc * 32 + lc] = acc[g][nc][r];
        }
  };
  auto ad = [&](const float* Sb) {
    #pragma unroll
    for (int g = 0; g < 2; ++g)
      #pragma unroll
      for (int nc = 0; nc < 4; ++nc)
        #pragma unroll
        for (int r = 0; r < 16; ++r) {
          int row = g * 32 + (r & 3) + 8 * (r >> 2) + 4 * lk;
          acc[g][nc][r] += Sb[row * 128 + nc * 32 + lc];
        }
  };
  __syncthreads();
  if (wave == 1) st(S0);
  if (wave == 3) st(S1);
  __syncthreads();
  if (wave == 0) ad(S0);            // 0+1
  if (wave == 2) ad(S1);            // 2+3
  __syncthreads();
  if (wave == 5) st(S0);
  if (wave == 7) st(S1);
  __syncthreads();
  if (wave == 4) ad(S0);            // 4+5
  if (wave == 6) ad(S1);            // 6+7
  __syncthreads();
  if (wave == 2) st(S0);
  if (wave == 6) st(S1);
  __syncthreads();
  if (wave == 0) ad(S0);            // 0..3
  if (wave == 4) ad(S1);            // 4..7
  __syncthreads();
  if (wave == 4) st(S0);
  __syncthreads();
  if (wave == 0) { ad(S0); st(S0); }   // full half-K sum -> S0
  __syncthreads();

  // coalesced copy S0 -> hp[(sid*2+s)*524288 + m*8192 .. +8192)
  {
    float* dst = hp + (size_t)((sid * 2 + s) * 524288 + m * 8192);
    #pragma unroll
    for (int q = 0; q < 4; ++q)
      *(float4*)(dst + t * 16 + q * 4) = *(const float4*)(S0 + t * 16 + q * 4);
  }
}

// ---------- phase2: layer2 + final dot, block = (sid, 32-row tile m2) ----------
__global__ __launch_bounds__(512) void phase2_kernel(
    const uint4* __restrict__ B2fx, const uint4* __restrict__ B2fy,
    const float* __restrict__ hp,
    const float* __restrict__ b1x_, const float* __restrict__ b1y_,
    const float* __restrict__ b2x_, const float* __restrict__ b2y_,
    const float* __restrict__ finw, float* __restrict__ partial)
{
  __shared__ float h1s[32 * 136];   // 17.4 KB
  __shared__ float redw[8];

  const int t    = threadIdx.x;
  const int bid  = blockIdx.x;
  const int sid  = bid >> 7;
  const int m2   = bid & 127;
  const int wave = t >> 6;
  const int l    = t & 63;
  const int lc   = l & 31;
  const int lk   = l >> 5;

  const uint4* B2 = sid ? B2fy : B2fx;
  const float* b1 = sid ? b1y_ : b1x_;
  const float* b2 = sid ? b2y_ : b2x_;

  // h1 = hp_half0 + hp_half1 + b1
  {
    const float* hp0 = hp + (size_t)((sid * 2 + 0) * 524288 + m2 * 4096);
    const float* hp1 = hp + (size_t)((sid * 2 + 1) * 524288 + m2 * 4096);
    int flat = t * 8;
    int row = flat >> 7, cb = flat & 127;
    float4 a0 = *(const float4*)(hp0 + flat);
    float4 a1 = *(const float4*)(hp0 + flat + 4);
    float4 c0 = *(const float4*)(hp1 + flat);
    float4 c1 = *(const float4*)(hp1 + flat + 4);
    h1s[row * 136 + cb + 0] = a0.x + c0.x + b1[cb + 0];
    h1s[row * 136 + cb + 1] = a0.y + c0.y + b1[cb + 1];
    h1s[row * 136 + cb + 2] = a0.z + c0.z + b1[cb + 2];
    h1s[row * 136 + cb + 3] = a0.w + c0.w + b1[cb + 3];
    h1s[row * 136 + cb + 4] = a1.x + c1.x + b1[cb + 4];
    h1s[row * 136 + cb + 5] = a1.y + c1.y + b1[cb + 5];
    h1s[row * 136 + cb + 6] = a1.z + c1.z + b1[cb + 6];
    h1s[row * 136 + cb + 7] = a1.w + c1.w + b1[cb + 7];
  }
  __syncthreads();

  float hr[8];
  {
    int cb = wave * 16 + lk * 8;
    float4 v0 = *(const float4*)(h1s + lc * 136 + cb);
    float4 v1 = *(const float4*)(h1s + lc * 136 + cb + 4);
    hr[0]=v0.x; hr[1]=v0.y; hr[2]=v0.z; hr[3]=v0.w;
    hr[4]=v1.x; hr[5]=v1.y; hr[6]=v1.z; hr[7]=v1.w;
  }

  floatx16 acc2[2] = {};
  #pragma unroll 1
  for (int j = 0; j < 9; ++j) {
    const uint4* bp = B2 + (size_t)((wave * 9 + j) * 2) * 128 + l;
    uint4 bf[4];
    #pragma unroll
    for (int nc = 0; nc < 2; ++nc) {
      bf[nc * 2]     = bp[nc * 128];
      bf[nc * 2 + 1] = bp[nc * 128 + 64];
    }
    float f[8];
    if (j == 0) {
      #pragma unroll
      for (int i = 0; i < 8; ++i)
        f[i] = __fdividef(hr[i], 1.f + __expf(-hr[i]));
    } else {
      float g = -2.f + (float)(j - 1) * (4.f / 7.f);
      #pragma unroll
      for (int i = 0; i < 8; ++i) {
        float z = (hr[i] - g) * 1.75f;
        f[i] = __expf(-z * z);
      }
    }
    short8 ah;
    #pragma unroll
    for (int i = 0; i < 8; ++i) ah[i] = (short)f2bf(f[i]);
    #pragma unroll
    for (int nc = 0; nc < 2; ++nc) {
      short8 bh = __builtin_bit_cast(short8, bf[nc * 2]);
      short8 bl = __builtin_bit_cast(short8, bf[nc * 2 + 1]);
      acc2[nc] = __builtin_amdgcn_mfma_f32_32x32x16_bf16(ah, bh, acc2[nc], 0, 0, 0);
      acc2[nc] = __builtin_amdgcn_mfma_f32_32x32x16_bf16(ah, bl, acc2[nc], 0, 0, 0);
    }
  }

  // per-wave partial dot with final_w; cross-wave scalar sum
  const float* wf = finw + sid * 64;
  {
    float w0 = wf[lc], w1v = wf[32 + lc];
    float pz = 0.f;
    #pragma unroll
    for (int r = 0; r < 16; ++r) pz += acc2[0][r] * w0 + acc2[1][r] * w1v;
    #pragma unroll
    for (int off = 32; off > 0; off >>= 1) pz += __shfl_down(pz, off, 64);
    if (l == 0) redw[wave] = pz;
  }
  __syncthreads();
  if (wave == 0) {
    float v = (l < 8) ? redw[l] : 0.f;
    v += 32.f * b2[l] * wf[l];        // bias term: 32 rows x b2.wf
    #pragma unroll
    for (int off = 32; off > 0; off >>= 1) v += __shfl_down(v, off, 64);
    if (l == 0) partial[bid] = v;
  }
}

__global__ __launch_bounds__(256) void final_kernel(
    const float* __restrict__ partial, const float* __restrict__ finb,
    float* __restrict__ out)
{
  __shared__ float red[4][64];
  int t = threadIdx.x;
  int batch = (t & 127) >> 5;
  int slot  = (t >> 7) * 32 + (t & 31);
  red[batch][slot] = partial[t];
  __syncthreads();
  if (t < 4) {
    float s = 0.f;
    for (int i = 0; i < 64; ++i) s += red[t][i];
    out[t] = finb[0] + s * (1.0f / 1024.0f);
  }
}

extern "C" void kernel_launch(void* const* d_in, const int* in_sizes, int n_in,
                              void* d_out, int out_size, void* d_ws, size_t ws_size,
                              hipStream_t stream)
{
  (void)in_sizes; (void)n_in; (void)out_size; (void)ws_size;
  const float* x    = (const float*)d_in[0];
  const float* y    = (const float*)d_in[1];
  const float* bw1x = (const float*)d_in[2];
  const float* bb1x = (const float*)d_in[3];
  const float* sw1x = (const float*)d_in[4];
  const float* sb1x = (const float*)d_in[5];
  const float* bw2x = (const float*)d_in[6];
  const float* bb2x = (const float*)d_in[7];
  const float* sw2x = (const float*)d_in[8];
  const float* sb2x = (const float*)d_in[9];
  const float* bw1y = (const float*)d_in[10];
  const float* bb1y = (const float*)d_in[11];
  const float* sw1y = (const float*)d_in[12];
  const float* sb1y = (const float*)d_in[13];
  const float* bw2y = (const float*)d_in[14];
  const float* bb2y = (const float*)d_in[15];
  const float* sw2y = (const float*)d_in[16];
  const float* sb2y = (const float*)d_in[17];
  const float* finw = (const float*)d_in[18];
  const float* finb = (const float*)d_in[19];

  char* ws = (char*)d_ws;
  uint4* B1fx = (uint4*)(ws);                       // 73728 uint4 = 1179648 B
  uint4* B1fy = (uint4*)(ws + 1179648);
  uint4* B2fx = (uint4*)(ws + 2359296);             // 18432 uint4 = 294912 B
  uint4* B2fy = (uint4*)(ws + 2654208);
  float* hp   = (float*)(ws + 2949120);             // 4 * 524288 floats = 8 MB
  float* b1x  = (float*)(ws + 2949120 + 8388608);
  float* b1y  = b1x + 128;
  float* b2x  = b1y + 128;
  float* b2y  = b2x + 64;
  float* partial = b2y + 64;                        // 256 floats

  int prep_total = 2 * 36864 + 2 * 9216 + 384;      // 92544
  int prep_blocks = (prep_total + 255) / 256;
  hipLaunchKernelGGL(prep_frags, dim3(prep_blocks), dim3(256), 0, stream,
                     bw1x, sw1x, bb1x, sb1x, bw2x, sw2x, bb2x, sb2x,
                     bw1y, sw1y, bb1y, sb1y, bw2y, sw2y, bb2y, sb2y,
                     B1fx, B1fy, B2fx, B2fy, b1x, b1y, b2x, b2y);

  hipLaunchKernelGGL(phase1_kernel, dim3(256), dim3(512), 0, stream,
                     x, y, B1fx, B1fy, hp);

  hipLaunchKernelGGL(phase2_kernel, dim3(256), dim3(512), 0, stream,
                     B2fx, B2fy, hp, b1x, b1y, b2x, b2y, finw, partial);

  hipLaunchKernelGGL(final_kernel, dim3(1), dim3(256), 0, stream,
                     partial, finb, (float*)d_out);
}